// Round 4
// baseline (483.031 us; speedup 1.0000x reference)
//
#include <hip/hip_runtime.h>
#include <cstdint>

#define AS1 __attribute__((address_space(1)))
#define AS3 __attribute__((address_space(3)))

typedef _Float16 half8 __attribute__((ext_vector_type(8)));
typedef _Float16 half4_t __attribute__((ext_vector_type(4)));
typedef float v4f __attribute__((ext_vector_type(4)));

__device__ __forceinline__ void async_ld16(const void* g, void* l) {
  __builtin_amdgcn_global_load_lds((const AS1 uint32_t*)g, (AS3 uint32_t*)l, 16, 0, 0);
}

// T5 relative-position bucket for delta = k - q (bidirectional, 32 buckets, max_dist 128).
// Exact-boundary cases (n = 8,16,32,64) in integer arithmetic; n>=91 clamps; float path
// has >=0.015 margin in value space vs ~1e-6 fp32 error.
__device__ __forceinline__ int t5_bucket(int delta) {
  int n = -delta;  // n = q - k
  int ret = 0;
  if (n < 0) { ret = 16; n = -n; }
  if (n < 8) return n + ret;
  if (n >= 91) return 15 + ret;
  if ((n & (n - 1)) == 0) {
    int l = 31 - __clz(n);
    int v = 2 + 2 * l;
    return (v > 15 ? 15 : v) + ret;
  }
  int v = 8 + (int)(logf((float)n * 0.125f) * (8.0f / logf(16.0f)));
  return (v > 15 ? 15 : v) + ret;
}

// ---------------- fp32 -> fp16 convert (hidden states) ----------------
__global__ void k_cvt(const float* __restrict__ src, _Float16* __restrict__ dst) {
  int t = blockIdx.x * 256 + threadIdx.x;
  float4 f = ((const float4*)src)[t];
  half4_t h = {(_Float16)f.x, (_Float16)f.y, (_Float16)f.z, (_Float16)f.w};
  ((half4_t*)dst)[t] = h;
}

// ---------------- fp32 1024x1024 transpose -> fp16 (all 4 weights, z = which) ----------
__global__ void k_wt_all(const float* __restrict__ Wq, const float* __restrict__ Wk,
                         const float* __restrict__ Wv, const float* __restrict__ Wo,
                         _Float16* __restrict__ wqkvT, _Float16* __restrict__ woT) {
  __shared__ float tile[32][33];
  const int z = blockIdx.z;
  const float* src = (z == 0) ? Wq : (z == 1) ? Wk : (z == 2) ? Wv : Wo;
  _Float16* dst = (z < 3) ? (wqkvT + ((size_t)z << 20)) : woT;
  int tx = threadIdx.x, ty = threadIdx.y;
  int bx = blockIdx.x * 32, by = blockIdx.y * 32;
#pragma unroll
  for (int i = 0; i < 32; i += 8)
    tile[ty + i][tx] = src[(size_t)(by + ty + i) * 1024 + bx + tx];
  __syncthreads();
#pragma unroll
  for (int i = 0; i < 32; i += 8)
    dst[(size_t)(bx + ty + i) * 1024 + by + tx] = (_Float16)tile[tx][ty + i];
}

// ---------------- fp16 MFMA GEMM (m97 pattern): 128x128 tile, BK=32 ----------------
// F16OUT path: V-range blocks (n0 >= 2048) store transposed into vT instead of C.
template <bool F16OUT>
__global__ __launch_bounds__(256, 2) void k_gemm(const _Float16* __restrict__ A,
                                                 const _Float16* __restrict__ BT,
                                                 void* __restrict__ Cv,
                                                 _Float16* __restrict__ vT, int K, int ldc) {
  __shared__ __align__(16) _Float16 As[128 * 32];
  __shared__ __align__(16) _Float16 Bs[128 * 32];
  const int tid = threadIdx.x;
  const int wave = tid >> 6, lane = tid & 63;
  const int l15 = lane & 15, quad = lane >> 4;
  const int m0 = blockIdx.y * 128, n0 = blockIdx.x * 128;
  const int wm = (wave >> 1) * 64, wn = (wave & 1) * 64;
  const int r0 = tid >> 2, c0 = (tid & 3) * 8;
  v4f acc[4][4] = {};
  for (int k0 = 0; k0 < K; k0 += 32) {
    __syncthreads();
    async_ld16(A + (size_t)(m0 + r0) * K + k0 + c0, (char*)As + (size_t)(wave * 64) * 16);
    async_ld16(A + (size_t)(m0 + 64 + r0) * K + k0 + c0,
               (char*)As + (size_t)(256 + wave * 64) * 16);
    async_ld16(BT + (size_t)(n0 + r0) * K + k0 + c0, (char*)Bs + (size_t)(wave * 64) * 16);
    async_ld16(BT + (size_t)(n0 + 64 + r0) * K + k0 + c0,
               (char*)Bs + (size_t)(256 + wave * 64) * 16);
    __syncthreads();
    half8 af[4], bf[4];
#pragma unroll
    for (int mt = 0; mt < 4; ++mt)
      af[mt] = *(const half8*)(As + (wm + mt * 16 + l15) * 32 + quad * 8);
#pragma unroll
    for (int nt = 0; nt < 4; ++nt)
      bf[nt] = *(const half8*)(Bs + (wn + nt * 16 + l15) * 32 + quad * 8);
#pragma unroll
    for (int mt = 0; mt < 4; ++mt)
#pragma unroll
      for (int nt = 0; nt < 4; ++nt)
        acc[mt][nt] = __builtin_amdgcn_mfma_f32_16x16x32_f16(af[mt], bf[nt], acc[mt][nt], 0, 0, 0);
  }
  if (F16OUT && n0 >= 2048) {
    // V block: write vT[((b*16+h)*64+d)][s], 4 consecutive s per lane -> b64 stores
#pragma unroll
    for (int mt = 0; mt < 4; ++mt)
#pragma unroll
      for (int nt = 0; nt < 4; ++nt) {
        int col = n0 + wn + nt * 16 + l15 - 2048;  // h*64 + d
        int row0 = m0 + wm + mt * 16 + quad * 4;   // token
        int bb = row0 >> 11, s0 = row0 & 2047;
        half4_t hv = {(_Float16)acc[mt][nt][0], (_Float16)acc[mt][nt][1],
                      (_Float16)acc[mt][nt][2], (_Float16)acc[mt][nt][3]};
        *(half4_t*)(vT + ((size_t)bb * 1024 + col) * 2048 + s0) = hv;
      }
    return;
  }
#pragma unroll
  for (int mt = 0; mt < 4; ++mt)
#pragma unroll
    for (int nt = 0; nt < 4; ++nt)
#pragma unroll
      for (int r = 0; r < 4; ++r) {
        int row = m0 + wm + mt * 16 + quad * 4 + r;
        int col = n0 + wn + nt * 16 + l15;
        if (F16OUT)
          ((_Float16*)Cv)[(size_t)row * ldc + col] = (_Float16)acc[mt][nt][r];
        else
          ((float*)Cv)[(size_t)row * ldc + col] = acc[mt][nt][r];
      }
}

// ---------------- output projection GEMM: 128x64 tile ----------------
__global__ __launch_bounds__(256, 2) void k_gemm_n64(const _Float16* __restrict__ A,
                                                     const _Float16* __restrict__ BT,
                                                     float* __restrict__ C, int K, int ldc) {
  __shared__ __align__(16) _Float16 As[128 * 32];
  __shared__ __align__(16) _Float16 Bs[64 * 32];
  const int tid = threadIdx.x;
  const int wave = tid >> 6, lane = tid & 63;
  const int l15 = lane & 15, quad = lane >> 4;
  const int m0 = blockIdx.y * 128, n0 = blockIdx.x * 64;
  const int wm = (wave >> 1) * 64, wn = (wave & 1) * 32;
  const int r0 = tid >> 2, c0 = (tid & 3) * 8;
  v4f acc[4][2] = {};
  for (int k0 = 0; k0 < K; k0 += 32) {
    __syncthreads();
    async_ld16(A + (size_t)(m0 + r0) * K + k0 + c0, (char*)As + (size_t)(wave * 64) * 16);
    async_ld16(A + (size_t)(m0 + 64 + r0) * K + k0 + c0,
               (char*)As + (size_t)(256 + wave * 64) * 16);
    async_ld16(BT + (size_t)(n0 + r0) * K + k0 + c0, (char*)Bs + (size_t)(wave * 64) * 16);
    __syncthreads();
    half8 af[4], bf[2];
#pragma unroll
    for (int mt = 0; mt < 4; ++mt)
      af[mt] = *(const half8*)(As + (wm + mt * 16 + l15) * 32 + quad * 8);
#pragma unroll
    for (int nt = 0; nt < 2; ++nt)
      bf[nt] = *(const half8*)(Bs + (wn + nt * 16 + l15) * 32 + quad * 8);
#pragma unroll
    for (int mt = 0; mt < 4; ++mt)
#pragma unroll
      for (int nt = 0; nt < 2; ++nt)
        acc[mt][nt] = __builtin_amdgcn_mfma_f32_16x16x32_f16(af[mt], bf[nt], acc[mt][nt], 0, 0, 0);
  }
#pragma unroll
  for (int mt = 0; mt < 4; ++mt)
#pragma unroll
    for (int nt = 0; nt < 2; ++nt)
#pragma unroll
      for (int r = 0; r < 4; ++r)
        C[(size_t)(m0 + wm + mt * 16 + quad * 4 + r) * ldc + n0 + wn + nt * 16 + l15] =
            acc[mt][nt][r];
}

// ---------------- fused flash attention + position-bias writer ----------------
// grid (16, 16, 2): x<8 attn q-tile (q0=x*256, 4 waves x 64 q each);
// x in [8,16) bias writer blocks (1 MB coalesced float4 stores each).
// 2 blocks/CU -> typically one attn (LDS/MFMA) + one bias (HBM write) co-resident.
__global__ __launch_bounds__(256, 2) void k_attn_bias(const _Float16* __restrict__ qkv,
                                                      const _Float16* __restrict__ vT,
                                                      const float* __restrict__ mask,
                                                      const float* __restrict__ rel,
                                                      _Float16* __restrict__ ctx,
                                                      float* __restrict__ outb) {
  constexpr int S = 2048, LD = 3072;
  __shared__ __align__(16) _Float16 Ks[64 * 72];    // [kv][d] pad->LD 72
  __shared__ __align__(16) _Float16 VT[64 * 72];    // [d][kv]
  __shared__ __align__(16) _Float16 Psh[256 * 72];  // [q][kv] per-wave-owned rows
  __shared__ float btab[1024];                      // bias vs delta in [-512,511]
  const int tid = threadIdx.x, wave = tid >> 6, lane = tid & 63;
  const int l15 = lane & 15, quad = lane >> 4;
  const int h = blockIdx.y, b = blockIdx.z;

  for (int j = tid; j < 1024; j += 256) btab[j] = rel[t5_bucket(j - 512) * 16 + h];
  const float c_past = rel[15 * 16 + h];  // q - k >= 91
  const float c_fut = rel[31 * 16 + h];   // k - q >= 91
  __syncthreads();

  if (blockIdx.x >= 8) {
    // ---- bias writer: out[h][q][k], q in [b*1024, b*1024+1024), 1/8 slice each
    const int blk = blockIdx.x - 8;  // 0..7
    float4* op = (float4*)outb + (size_t)h * 2048 * 512;
#pragma unroll 4
    for (int i = 0; i < 256; ++i) {
      int idx = blk * 65536 + i * 256 + tid;  // within (h, half): 1024 q x 512 k4
      int k4 = idx & 511;
      int q = b * 1024 + (idx >> 9);
      int kb = k4 * 4;
      float4 v;
      if (kb - q >= 91) {
        v = make_float4(c_fut, c_fut, c_fut, c_fut);
      } else if (q - kb - 3 >= 91) {
        v = make_float4(c_past, c_past, c_past, c_past);
      } else {
        v.x = btab[kb + 0 - q + 512];
        v.y = btab[kb + 1 - q + 512];
        v.z = btab[kb + 2 - q + 512];
        v.w = btab[kb + 3 - q + 512];
      }
      op[(size_t)q * 512 + k4] = v;
    }
    return;
  }

  // ---- attention path: operand-swapped flash, each wave owns 64 q (qt=0..3) ----
  const int q0 = blockIdx.x * 256;
  const int qbase = q0 + wave * 64;  // this wave's q range [qbase, qbase+64)

  half8 bq[4][2];
#pragma unroll
  for (int qt = 0; qt < 4; ++qt) {
    const _Float16* qp = qkv + (size_t)(b * S + qbase + qt * 16 + l15) * LD + h * 64;
    bq[qt][0] = *(const half8*)(qp + quad * 8);
    bq[qt][1] = *(const half8*)(qp + 32 + quad * 8);
  }
  v4f o[4][4] = {};
  float mrun[4] = {-INFINITY, -INFINITY, -INFINITY, -INFINITY};
  float lrun[4] = {0.f, 0.f, 0.f, 0.f};

  const int srow = tid >> 2, scol = (tid & 3) * 8;
  const _Float16* kg = qkv + (size_t)(b * S + srow) * LD + 1024 + h * 64 + scol;
  const _Float16* vg = vT + ((size_t)((b * 16 + h) * 64 + srow)) * S + scol;
  const float4* mkp = (const float4*)(mask + (size_t)b * S);

  for (int kv0 = 0; kv0 < S; kv0 += 64) {
    // global prefetch overlaps the barrier wait
    half8 kr0 = *(const half8*)(kg + (size_t)kv0 * LD);
    half8 kr1 = *(const half8*)(kg + (size_t)kv0 * LD + 32);
    half8 vr0 = *(const half8*)(vg + kv0);
    half8 vr1 = *(const half8*)(vg + kv0 + 32);
    float4 mk[4];
#pragma unroll
    for (int mt = 0; mt < 4; ++mt) mk[mt] = mkp[(kv0 >> 2) + mt * 4 + quad];
    __syncthreads();  // prev-iter Ks/VT reads done
    *(half8*)(Ks + srow * 72 + scol) = kr0;
    *(half8*)(Ks + srow * 72 + scol + 32) = kr1;
    *(half8*)(VT + srow * 72 + scol) = vr0;
    *(half8*)(VT + srow * 72 + scol + 32) = vr1;
    __syncthreads();  // staging visible

    // S^T: sc[qt][mt][r] = score(kv = kv0+mt*16+quad*4+r, q = qbase+qt*16+l15)
    // af loaded once per (kc,mt), reused across 4 qt -> 8 LDS reads for 32 MFMA
    v4f sc[4][4] = {};
#pragma unroll
    for (int kc = 0; kc < 2; ++kc)
#pragma unroll
      for (int mt = 0; mt < 4; ++mt) {
        half8 af = *(const half8*)(Ks + (mt * 16 + l15) * 72 + kc * 32 + quad * 8);
#pragma unroll
        for (int qt = 0; qt < 4; ++qt)
          sc[qt][mt] = __builtin_amdgcn_mfma_f32_16x16x32_f16(af, bq[qt][kc], sc[qt][mt], 0, 0, 0);
      }

    // bias + mask; block-uniform tile classification over 256-wide q range
    const int diff = kv0 - q0;
    const bool mixed = (diff >= -153) && (diff <= 345);
    const float cf = (diff > 345) ? c_fut : c_past;
    v4f cm[4];
#pragma unroll
    for (int mt = 0; mt < 4; ++mt) {
      cm[mt][0] = mk[mt].x; cm[mt][1] = mk[mt].y; cm[mt][2] = mk[mt].z; cm[mt][3] = mk[mt].w;
      if (!mixed) {
        cm[mt][0] += cf; cm[mt][1] += cf; cm[mt][2] += cf; cm[mt][3] += cf;
      }
    }
    if (mixed) {
#pragma unroll
      for (int qt = 0; qt < 4; ++qt) {
        const int qq = qbase + qt * 16 + l15;
#pragma unroll
        for (int mt = 0; mt < 4; ++mt) {
          int base = kv0 + mt * 16 + quad * 4 - qq + 512;
#pragma unroll
          for (int r = 0; r < 4; ++r) sc[qt][mt][r] += btab[base + r] + cm[mt][r];
        }
      }
    } else {
#pragma unroll
      for (int qt = 0; qt < 4; ++qt)
#pragma unroll
        for (int mt = 0; mt < 4; ++mt)
#pragma unroll
          for (int r = 0; r < 4; ++r) sc[qt][mt][r] += cm[mt][r];
    }

    // online softmax (one q per lane per qt; reduce across quads: xor 16, 32)
#pragma unroll
    for (int qt = 0; qt < 4; ++qt) {
      v4f m4 = sc[qt][0];
#pragma unroll
      for (int r = 0; r < 4; ++r) {
        m4[r] = fmaxf(m4[r], sc[qt][1][r]);
        m4[r] = fmaxf(m4[r], sc[qt][2][r]);
        m4[r] = fmaxf(m4[r], sc[qt][3][r]);
      }
      float mx = fmaxf(fmaxf(m4[0], m4[1]), fmaxf(m4[2], m4[3]));
      mx = fmaxf(mx, __shfl_xor(mx, 16, 64));
      mx = fmaxf(mx, __shfl_xor(mx, 32, 64));
      float mnew = fmaxf(mrun[qt], mx);
      float alpha = __expf(mrun[qt] - mnew);
      mrun[qt] = mnew;
      v4f s4 = {};
#pragma unroll
      for (int mt = 0; mt < 4; ++mt)
#pragma unroll
        for (int r = 0; r < 4; ++r) {
          float p = __expf(sc[qt][mt][r] - mnew);
          sc[qt][mt][r] = p;
          s4[r] += p;
        }
      float rs = (s4[0] + s4[1]) + (s4[2] + s4[3]);
      rs += __shfl_xor(rs, 16, 64);
      rs += __shfl_xor(rs, 32, 64);
      lrun[qt] = lrun[qt] * alpha + rs;
#pragma unroll
      for (int dt = 0; dt < 4; ++dt)
#pragma unroll
        for (int r = 0; r < 4; ++r) o[qt][dt][r] *= alpha;
      // P write: 4 consecutive kv per lane -> packed b64 (own-wave rows only)
      const int prow = wave * 64 + qt * 16 + l15;
#pragma unroll
      for (int mt = 0; mt < 4; ++mt) {
        half4_t ph = {(_Float16)sc[qt][mt][0], (_Float16)sc[qt][mt][1],
                      (_Float16)sc[qt][mt][2], (_Float16)sc[qt][mt][3]};
        *(half4_t*)(Psh + prow * 72 + mt * 16 + quad * 4) = ph;
      }
    }
    // NO barrier: PV reads only this wave's own P rows (same-wave LDS RAW -> lgkmcnt)

    // O^T += V^T * P^T ; av loaded once per (dt,kc), reused across 4 qt
#pragma unroll
    for (int kc = 0; kc < 2; ++kc) {
      half8 av[4];
#pragma unroll
      for (int dt = 0; dt < 4; ++dt)
        av[dt] = *(const half8*)(VT + (dt * 16 + l15) * 72 + kc * 32 + quad * 8);
#pragma unroll
      for (int qt = 0; qt < 4; ++qt) {
        half8 bp = *(const half8*)(Psh + (wave * 64 + qt * 16 + l15) * 72 + kc * 32 + quad * 8);
#pragma unroll
        for (int dt = 0; dt < 4; ++dt)
          o[qt][dt] = __builtin_amdgcn_mfma_f32_16x16x32_f16(av[dt], bp, o[qt][dt], 0, 0, 0);
      }
    }
  }
  // epilogue: ctx[token][h*64+d], d = dt*16 + quad*4 + r
#pragma unroll
  for (int qt = 0; qt < 4; ++qt) {
    float inv = 1.0f / lrun[qt];
    const size_t token = (size_t)(b * S + qbase + qt * 16 + l15);
#pragma unroll
    for (int dt = 0; dt < 4; ++dt) {
      half4_t hv = {(_Float16)(o[qt][dt][0] * inv), (_Float16)(o[qt][dt][1] * inv),
                    (_Float16)(o[qt][dt][2] * inv), (_Float16)(o[qt][dt][3] * inv)};
      *(half4_t*)(ctx + token * 1024 + h * 64 + dt * 16 + quad * 4) = hv;
    }
  }
}

extern "C" void kernel_launch(void* const* d_in, const int* in_sizes, int n_in,
                              void* d_out, int out_size, void* d_ws, size_t ws_size,
                              hipStream_t stream) {
  const float* hs = (const float*)d_in[0];
  const float* mask = (const float*)d_in[1];
  const float* Wq = (const float*)d_in[2];
  const float* Wk = (const float*)d_in[3];
  const float* Wv = (const float*)d_in[4];
  const float* Wo = (const float*)d_in[5];
  const float* rel = (const float*)d_in[6];
  float* out = (float*)d_out;

  // workspace layout (56 MB)
  char* ws = (char*)d_ws;
  _Float16* hsF = (_Float16*)(ws);                 // [4096,1024]   8 MB
  _Float16* wqkvT = (_Float16*)(ws + (8u << 20));  // [3072,1024]   6 MB
  _Float16* woT = (_Float16*)(ws + (14u << 20));   // [1024,1024]   2 MB
  _Float16* qkv = (_Float16*)(ws + (16u << 20));   // [4096,3072]  24 MB (V-part unused)
  _Float16* ctx = (_Float16*)(ws + (40u << 20));   // [4096,1024]   8 MB
  _Float16* vT = (_Float16*)(ws + (48u << 20));    // [2,16,64,2048] 8 MB

  k_cvt<<<4096, 256, 0, stream>>>(hs, hsF);
  k_wt_all<<<dim3(32, 32, 4), dim3(32, 8), 0, stream>>>(Wq, Wk, Wv, Wo, wqkvT, woT);

  // QKV projection; V-range blocks write vT directly (transposed epilogue)
  k_gemm<true><<<dim3(24, 32), 256, 0, stream>>>(hsF, wqkvT, qkv, vT, 1024, 3072);
  // fused attention (256 q/block, 64 q/wave) + position-bias writer
  k_attn_bias<<<dim3(16, 16, 2), 256, 0, stream>>>(qkv, vT, mask, rel, ctx, out + 4194304);
  // output projection
  k_gemm_n64<<<dim3(16, 32), 256, 0, stream>>>(ctx, woT, out, 1024, 1024);
}

// Round 5
// 455.862 us; speedup vs baseline: 1.0596x; 1.0596x over previous
//
#include <hip/hip_runtime.h>
#include <cstdint>

#define AS1 __attribute__((address_space(1)))
#define AS3 __attribute__((address_space(3)))

typedef _Float16 half8 __attribute__((ext_vector_type(8)));
typedef _Float16 half4_t __attribute__((ext_vector_type(4)));
typedef float v4f __attribute__((ext_vector_type(4)));

__device__ __forceinline__ void async_ld16(const void* g, void* l) {
  __builtin_amdgcn_global_load_lds((const AS1 uint32_t*)g, (AS3 uint32_t*)l, 16, 0, 0);
}

// T5 relative-position bucket for delta = k - q (bidirectional, 32 buckets, max_dist 128).
// Exact-boundary cases (n = 8,16,32,64) in integer arithmetic; n>=91 clamps; float path
// has >=0.015 margin in value space vs ~1e-6 fp32 error.
__device__ __forceinline__ int t5_bucket(int delta) {
  int n = -delta;  // n = q - k
  int ret = 0;
  if (n < 0) { ret = 16; n = -n; }
  if (n < 8) return n + ret;
  if (n >= 91) return 15 + ret;
  if ((n & (n - 1)) == 0) {
    int l = 31 - __clz(n);
    int v = 2 + 2 * l;
    return (v > 15 ? 15 : v) + ret;
  }
  int v = 8 + (int)(logf((float)n * 0.125f) * (8.0f / logf(16.0f)));
  return (v > 15 ? 15 : v) + ret;
}

// ---------------- fp32 -> fp16 convert (hidden states) ----------------
__global__ void k_cvt(const float* __restrict__ src, _Float16* __restrict__ dst) {
  int t = blockIdx.x * 256 + threadIdx.x;
  float4 f = ((const float4*)src)[t];
  half4_t h = {(_Float16)f.x, (_Float16)f.y, (_Float16)f.z, (_Float16)f.w};
  ((half4_t*)dst)[t] = h;
}

// ---------------- fp32 1024x1024 transpose -> fp16 (all 4 weights, z = which) ----------
__global__ void k_wt_all(const float* __restrict__ Wq, const float* __restrict__ Wk,
                         const float* __restrict__ Wv, const float* __restrict__ Wo,
                         _Float16* __restrict__ wqkvT, _Float16* __restrict__ woT) {
  __shared__ float tile[32][33];
  const int z = blockIdx.z;
  const float* src = (z == 0) ? Wq : (z == 1) ? Wk : (z == 2) ? Wv : Wo;
  _Float16* dst = (z < 3) ? (wqkvT + ((size_t)z << 20)) : woT;
  int tx = threadIdx.x, ty = threadIdx.y;
  int bx = blockIdx.x * 32, by = blockIdx.y * 32;
#pragma unroll
  for (int i = 0; i < 32; i += 8)
    tile[ty + i][tx] = src[(size_t)(by + ty + i) * 1024 + bx + tx];
  __syncthreads();
#pragma unroll
  for (int i = 0; i < 32; i += 8)
    dst[(size_t)(bx + ty + i) * 1024 + by + tx] = (_Float16)tile[tx][ty + i];
}

// ---------------- fp16 MFMA GEMM (m97 pattern): 128x128 tile, BK=32 ----------------
// F16OUT path: V-range blocks (n0 >= 2048) store transposed into vT instead of C.
template <bool F16OUT>
__global__ __launch_bounds__(256, 2) void k_gemm(const _Float16* __restrict__ A,
                                                 const _Float16* __restrict__ BT,
                                                 void* __restrict__ Cv,
                                                 _Float16* __restrict__ vT, int K, int ldc) {
  __shared__ __align__(16) _Float16 As[128 * 32];
  __shared__ __align__(16) _Float16 Bs[128 * 32];
  const int tid = threadIdx.x;
  const int wave = tid >> 6, lane = tid & 63;
  const int l15 = lane & 15, quad = lane >> 4;
  const int m0 = blockIdx.y * 128, n0 = blockIdx.x * 128;
  const int wm = (wave >> 1) * 64, wn = (wave & 1) * 64;
  const int r0 = tid >> 2, c0 = (tid & 3) * 8;
  v4f acc[4][4] = {};
  for (int k0 = 0; k0 < K; k0 += 32) {
    __syncthreads();
    async_ld16(A + (size_t)(m0 + r0) * K + k0 + c0, (char*)As + (size_t)(wave * 64) * 16);
    async_ld16(A + (size_t)(m0 + 64 + r0) * K + k0 + c0,
               (char*)As + (size_t)(256 + wave * 64) * 16);
    async_ld16(BT + (size_t)(n0 + r0) * K + k0 + c0, (char*)Bs + (size_t)(wave * 64) * 16);
    async_ld16(BT + (size_t)(n0 + 64 + r0) * K + k0 + c0,
               (char*)Bs + (size_t)(256 + wave * 64) * 16);
    __syncthreads();
    half8 af[4], bf[4];
#pragma unroll
    for (int mt = 0; mt < 4; ++mt)
      af[mt] = *(const half8*)(As + (wm + mt * 16 + l15) * 32 + quad * 8);
#pragma unroll
    for (int nt = 0; nt < 4; ++nt)
      bf[nt] = *(const half8*)(Bs + (wn + nt * 16 + l15) * 32 + quad * 8);
#pragma unroll
    for (int mt = 0; mt < 4; ++mt)
#pragma unroll
      for (int nt = 0; nt < 4; ++nt)
        acc[mt][nt] = __builtin_amdgcn_mfma_f32_16x16x32_f16(af[mt], bf[nt], acc[mt][nt], 0, 0, 0);
  }
  if (F16OUT && n0 >= 2048) {
    // V block: write vT[((b*16+h)*64+d)][s], 4 consecutive s per lane -> b64 stores
#pragma unroll
    for (int mt = 0; mt < 4; ++mt)
#pragma unroll
      for (int nt = 0; nt < 4; ++nt) {
        int col = n0 + wn + nt * 16 + l15 - 2048;  // h*64 + d
        int row0 = m0 + wm + mt * 16 + quad * 4;   // token
        int bb = row0 >> 11, s0 = row0 & 2047;
        half4_t hv = {(_Float16)acc[mt][nt][0], (_Float16)acc[mt][nt][1],
                      (_Float16)acc[mt][nt][2], (_Float16)acc[mt][nt][3]};
        *(half4_t*)(vT + ((size_t)bb * 1024 + col) * 2048 + s0) = hv;
      }
    return;
  }
#pragma unroll
  for (int mt = 0; mt < 4; ++mt)
#pragma unroll
    for (int nt = 0; nt < 4; ++nt)
#pragma unroll
      for (int r = 0; r < 4; ++r) {
        int row = m0 + wm + mt * 16 + quad * 4 + r;
        int col = n0 + wn + nt * 16 + l15;
        if (F16OUT)
          ((_Float16*)Cv)[(size_t)row * ldc + col] = (_Float16)acc[mt][nt][r];
        else
          ((float*)Cv)[(size_t)row * ldc + col] = acc[mt][nt][r];
      }
}

// ---------------- output projection GEMM: 128x64 tile ----------------
__global__ __launch_bounds__(256, 2) void k_gemm_n64(const _Float16* __restrict__ A,
                                                     const _Float16* __restrict__ BT,
                                                     float* __restrict__ C, int K, int ldc) {
  __shared__ __align__(16) _Float16 As[128 * 32];
  __shared__ __align__(16) _Float16 Bs[64 * 32];
  const int tid = threadIdx.x;
  const int wave = tid >> 6, lane = tid & 63;
  const int l15 = lane & 15, quad = lane >> 4;
  const int m0 = blockIdx.y * 128, n0 = blockIdx.x * 64;
  const int wm = (wave >> 1) * 64, wn = (wave & 1) * 32;
  const int r0 = tid >> 2, c0 = (tid & 3) * 8;
  v4f acc[4][2] = {};
  for (int k0 = 0; k0 < K; k0 += 32) {
    __syncthreads();
    async_ld16(A + (size_t)(m0 + r0) * K + k0 + c0, (char*)As + (size_t)(wave * 64) * 16);
    async_ld16(A + (size_t)(m0 + 64 + r0) * K + k0 + c0,
               (char*)As + (size_t)(256 + wave * 64) * 16);
    async_ld16(BT + (size_t)(n0 + r0) * K + k0 + c0, (char*)Bs + (size_t)(wave * 64) * 16);
    __syncthreads();
    half8 af[4], bf[2];
#pragma unroll
    for (int mt = 0; mt < 4; ++mt)
      af[mt] = *(const half8*)(As + (wm + mt * 16 + l15) * 32 + quad * 8);
#pragma unroll
    for (int nt = 0; nt < 2; ++nt)
      bf[nt] = *(const half8*)(Bs + (wn + nt * 16 + l15) * 32 + quad * 8);
#pragma unroll
    for (int mt = 0; mt < 4; ++mt)
#pragma unroll
      for (int nt = 0; nt < 2; ++nt)
        acc[mt][nt] = __builtin_amdgcn_mfma_f32_16x16x32_f16(af[mt], bf[nt], acc[mt][nt], 0, 0, 0);
  }
#pragma unroll
  for (int mt = 0; mt < 4; ++mt)
#pragma unroll
    for (int nt = 0; nt < 2; ++nt)
#pragma unroll
      for (int r = 0; r < 4; ++r)
        C[(size_t)(m0 + wm + mt * 16 + quad * 4 + r) * ldc + n0 + wn + nt * 16 + l15] =
            acc[mt][nt][r];
}

// ---------------- fused flash attention WITH in-loop position-bias writes ----------------
// grid (8, 16, 2) = 256 blocks = 1/CU, __launch_bounds__(256,1) (no VGPR cap spills).
// Each block: attn for q in [x*256, x*256+256) of (h,b), AND writes the bias slice
// out[h][q-range][k-half(b)] (1 MB) spread over the 32 kv iterations -> the streaming
// HBM writes drain underneath the LDS/MFMA/VALU attn work (separate pipes).
__global__ __launch_bounds__(256, 1) void k_attn_bias(const _Float16* __restrict__ qkv,
                                                      const _Float16* __restrict__ vT,
                                                      const float* __restrict__ mask,
                                                      const float* __restrict__ rel,
                                                      _Float16* __restrict__ ctx,
                                                      float* __restrict__ outb) {
  constexpr int S = 2048, LD = 3072;
  __shared__ __align__(16) _Float16 Ks[64 * 72];    // [kv][d] pad->LD 72
  __shared__ __align__(16) _Float16 VT[64 * 72];    // [d][kv]
  __shared__ __align__(16) _Float16 Psh[256 * 72];  // [q][kv] per-wave-owned rows
  __shared__ float btab[1024];                      // bias vs delta in [-512,511]
  const int tid = threadIdx.x, wave = tid >> 6, lane = tid & 63;
  const int l15 = lane & 15, quad = lane >> 4;
  const int h = blockIdx.y, b = blockIdx.z;

  for (int j = tid; j < 1024; j += 256) btab[j] = rel[t5_bucket(j - 512) * 16 + h];
  const float c_past = rel[15 * 16 + h];  // q - k >= 91
  const float c_fut = rel[31 * 16 + h];   // k - q >= 91
  __syncthreads();

  const int q0 = blockIdx.x * 256;
  const int qbase = q0 + wave * 64;  // this wave's q range [qbase, qbase+64)

  half8 bq[4][2];
#pragma unroll
  for (int qt = 0; qt < 4; ++qt) {
    const _Float16* qp = qkv + (size_t)(b * S + qbase + qt * 16 + l15) * LD + h * 64;
    bq[qt][0] = *(const half8*)(qp + quad * 8);
    bq[qt][1] = *(const half8*)(qp + 32 + quad * 8);
  }
  v4f o[4][4] = {};
  float mrun[4] = {-INFINITY, -INFINITY, -INFINITY, -INFINITY};
  float lrun[4] = {0.f, 0.f, 0.f, 0.f};

  const int srow = tid >> 2, scol = (tid & 3) * 8;
  const _Float16* kg = qkv + (size_t)(b * S + srow) * LD + 1024 + h * 64 + scol;
  const _Float16* vg = vT + ((size_t)((b * 16 + h) * 64 + srow)) * S + scol;
  const float4* mkp = (const float4*)(mask + (size_t)b * S);
  // bias slice base for this block: out[h][.][.], float4 granularity
  float4* const obase = (float4*)outb + (size_t)h * 2048 * 512;
  const int brow = tid >> 5;        // 0..7: q-row within this iter's 8-row bias strip
  const int bcol0 = tid & 31;       // float4 col 0..31 (x8 unrolled)

  for (int kv0 = 0; kv0 < S; kv0 += 64) {
    const int iter = kv0 >> 6;  // 0..31
    // global prefetch overlaps the barrier wait
    half8 kr0 = *(const half8*)(kg + (size_t)kv0 * LD);
    half8 kr1 = *(const half8*)(kg + (size_t)kv0 * LD + 32);
    half8 vr0 = *(const half8*)(vg + kv0);
    half8 vr1 = *(const half8*)(vg + kv0 + 32);
    float4 mk[4];
#pragma unroll
    for (int mt = 0; mt < 4; ++mt) mk[mt] = mkp[(kv0 >> 2) + mt * 4 + quad];
    __syncthreads();  // prev-iter Ks/VT reads done
    *(half8*)(Ks + srow * 72 + scol) = kr0;
    *(half8*)(Ks + srow * 72 + scol + 32) = kr1;
    *(half8*)(VT + srow * 72 + scol) = vr0;
    *(half8*)(VT + srow * 72 + scol + 32) = vr1;
    __syncthreads();  // staging visible

    // ---- bias strip: 8 q-rows x this b's 1024-k half (32 KB), coalesced 512B runs ----
    {
      const int qr = q0 + iter * 8 + brow;
      float4* orow = obase + (size_t)qr * 512 + b * 256;
#pragma unroll
      for (int j = 0; j < 8; ++j) {
        int c4 = bcol0 + j * 32;          // float4 col within half: 0..255
        int kb = (b * 256 + c4) * 4;      // k element base
        float4 v;
        if (kb - qr >= 91) {
          v = make_float4(c_fut, c_fut, c_fut, c_fut);
        } else if (qr - kb - 3 >= 91) {
          v = make_float4(c_past, c_past, c_past, c_past);
        } else {
          v.x = btab[kb + 0 - qr + 512];
          v.y = btab[kb + 1 - qr + 512];
          v.z = btab[kb + 2 - qr + 512];
          v.w = btab[kb + 3 - qr + 512];
        }
        orow[c4] = v;
      }
    }

    // S^T: sc[qt][mt][r] = score(kv = kv0+mt*16+quad*4+r, q = qbase+qt*16+l15)
    v4f sc[4][4] = {};
#pragma unroll
    for (int kc = 0; kc < 2; ++kc)
#pragma unroll
      for (int mt = 0; mt < 4; ++mt) {
        half8 af = *(const half8*)(Ks + (mt * 16 + l15) * 72 + kc * 32 + quad * 8);
#pragma unroll
        for (int qt = 0; qt < 4; ++qt)
          sc[qt][mt] = __builtin_amdgcn_mfma_f32_16x16x32_f16(af, bq[qt][kc], sc[qt][mt], 0, 0, 0);
      }

    // bias + mask; block-uniform tile classification over 256-wide q range
    const int diff = kv0 - q0;
    const bool mixed = (diff >= -153) && (diff <= 345);
    const float cf = (diff > 345) ? c_fut : c_past;
    v4f cm[4];
#pragma unroll
    for (int mt = 0; mt < 4; ++mt) {
      cm[mt][0] = mk[mt].x; cm[mt][1] = mk[mt].y; cm[mt][2] = mk[mt].z; cm[mt][3] = mk[mt].w;
      if (!mixed) {
        cm[mt][0] += cf; cm[mt][1] += cf; cm[mt][2] += cf; cm[mt][3] += cf;
      }
    }
    if (mixed) {
#pragma unroll
      for (int qt = 0; qt < 4; ++qt) {
        const int qq = qbase + qt * 16 + l15;
#pragma unroll
        for (int mt = 0; mt < 4; ++mt) {
          int base = kv0 + mt * 16 + quad * 4 - qq + 512;
#pragma unroll
          for (int r = 0; r < 4; ++r) sc[qt][mt][r] += btab[base + r] + cm[mt][r];
        }
      }
    } else {
#pragma unroll
      for (int qt = 0; qt < 4; ++qt)
#pragma unroll
        for (int mt = 0; mt < 4; ++mt)
#pragma unroll
          for (int r = 0; r < 4; ++r) sc[qt][mt][r] += cm[mt][r];
    }

    // online softmax (one q per lane per qt; reduce across quads: xor 16, 32)
#pragma unroll
    for (int qt = 0; qt < 4; ++qt) {
      v4f m4 = sc[qt][0];
#pragma unroll
      for (int r = 0; r < 4; ++r) {
        m4[r] = fmaxf(m4[r], sc[qt][1][r]);
        m4[r] = fmaxf(m4[r], sc[qt][2][r]);
        m4[r] = fmaxf(m4[r], sc[qt][3][r]);
      }
      float mx = fmaxf(fmaxf(m4[0], m4[1]), fmaxf(m4[2], m4[3]));
      mx = fmaxf(mx, __shfl_xor(mx, 16, 64));
      mx = fmaxf(mx, __shfl_xor(mx, 32, 64));
      float mnew = fmaxf(mrun[qt], mx);
      float alpha = __expf(mrun[qt] - mnew);
      mrun[qt] = mnew;
      v4f s4 = {};
#pragma unroll
      for (int mt = 0; mt < 4; ++mt)
#pragma unroll
        for (int r = 0; r < 4; ++r) {
          float p = __expf(sc[qt][mt][r] - mnew);
          sc[qt][mt][r] = p;
          s4[r] += p;
        }
      float rs = (s4[0] + s4[1]) + (s4[2] + s4[3]);
      rs += __shfl_xor(rs, 16, 64);
      rs += __shfl_xor(rs, 32, 64);
      lrun[qt] = lrun[qt] * alpha + rs;
#pragma unroll
      for (int dt = 0; dt < 4; ++dt)
#pragma unroll
        for (int r = 0; r < 4; ++r) o[qt][dt][r] *= alpha;
      // P write: 4 consecutive kv per lane -> packed b64 (own-wave rows only)
      const int prow = wave * 64 + qt * 16 + l15;
#pragma unroll
      for (int mt = 0; mt < 4; ++mt) {
        half4_t ph = {(_Float16)sc[qt][mt][0], (_Float16)sc[qt][mt][1],
                      (_Float16)sc[qt][mt][2], (_Float16)sc[qt][mt][3]};
        *(half4_t*)(Psh + prow * 72 + mt * 16 + quad * 4) = ph;
      }
    }
    // NO barrier: PV reads only this wave's own P rows (same-wave LDS RAW -> lgkmcnt)

    // O^T += V^T * P^T ; av loaded once per (dt,kc), reused across 4 qt
#pragma unroll
    for (int kc = 0; kc < 2; ++kc) {
      half8 av[4];
#pragma unroll
      for (int dt = 0; dt < 4; ++dt)
        av[dt] = *(const half8*)(VT + (dt * 16 + l15) * 72 + kc * 32 + quad * 8);
#pragma unroll
      for (int qt = 0; qt < 4; ++qt) {
        half8 bp = *(const half8*)(Psh + (wave * 64 + qt * 16 + l15) * 72 + kc * 32 + quad * 8);
#pragma unroll
        for (int dt = 0; dt < 4; ++dt)
          o[qt][dt] = __builtin_amdgcn_mfma_f32_16x16x32_f16(av[dt], bp, o[qt][dt], 0, 0, 0);
      }
    }
  }
  // epilogue: ctx[token][h*64+d], d = dt*16 + quad*4 + r
#pragma unroll
  for (int qt = 0; qt < 4; ++qt) {
    float inv = 1.0f / lrun[qt];
    const size_t token = (size_t)(b * S + qbase + qt * 16 + l15);
#pragma unroll
    for (int dt = 0; dt < 4; ++dt) {
      half4_t hv = {(_Float16)(o[qt][dt][0] * inv), (_Float16)(o[qt][dt][1] * inv),
                    (_Float16)(o[qt][dt][2] * inv), (_Float16)(o[qt][dt][3] * inv)};
      *(half4_t*)(ctx + token * 1024 + h * 64 + dt * 16 + quad * 4) = hv;
    }
  }
}

extern "C" void kernel_launch(void* const* d_in, const int* in_sizes, int n_in,
                              void* d_out, int out_size, void* d_ws, size_t ws_size,
                              hipStream_t stream) {
  const float* hs = (const float*)d_in[0];
  const float* mask = (const float*)d_in[1];
  const float* Wq = (const float*)d_in[2];
  const float* Wk = (const float*)d_in[3];
  const float* Wv = (const float*)d_in[4];
  const float* Wo = (const float*)d_in[5];
  const float* rel = (const float*)d_in[6];
  float* out = (float*)d_out;

  // workspace layout (56 MB)
  char* ws = (char*)d_ws;
  _Float16* hsF = (_Float16*)(ws);                 // [4096,1024]   8 MB
  _Float16* wqkvT = (_Float16*)(ws + (8u << 20));  // [3072,1024]   6 MB
  _Float16* woT = (_Float16*)(ws + (14u << 20));   // [1024,1024]   2 MB
  _Float16* qkv = (_Float16*)(ws + (16u << 20));   // [4096,3072]  24 MB (V-part unused)
  _Float16* ctx = (_Float16*)(ws + (40u << 20));   // [4096,1024]   8 MB
  _Float16* vT = (_Float16*)(ws + (48u << 20));    // [2,16,64,2048] 8 MB

  k_cvt<<<4096, 256, 0, stream>>>(hs, hsF);
  k_wt_all<<<dim3(32, 32, 4), dim3(32, 8), 0, stream>>>(Wq, Wk, Wv, Wo, wqkvT, woT);

  // QKV projection; V-range blocks write vT directly (transposed epilogue)
  k_gemm<true><<<dim3(24, 32), 256, 0, stream>>>(hsF, wqkvT, qkv, vT, 1024, 3072);
  // fused attention (256 q/block, 64 q/wave) + in-loop bias slice writes; 1 block/CU
  k_attn_bias<<<dim3(8, 16, 2), 256, 0, stream>>>(qkv, vT, mask, rel, ctx, out + 4194304);
  // output projection
  k_gemm_n64<<<dim3(16, 32), 256, 0, stream>>>(ctx, woT, out, 1024, 1024);
}

// Round 6
// 435.234 us; speedup vs baseline: 1.1098x; 1.0474x over previous
//
#include <hip/hip_runtime.h>
#include <cstdint>

#define AS1 __attribute__((address_space(1)))
#define AS3 __attribute__((address_space(3)))

typedef _Float16 half8 __attribute__((ext_vector_type(8)));
typedef _Float16 half4_t __attribute__((ext_vector_type(4)));
typedef float v4f __attribute__((ext_vector_type(4)));

__device__ __forceinline__ void async_ld16(const void* g, void* l) {
  __builtin_amdgcn_global_load_lds((const AS1 uint32_t*)g, (AS3 uint32_t*)l, 16, 0, 0);
}

// T5 relative-position bucket for delta = k - q (bidirectional, 32 buckets, max_dist 128).
// Exact-boundary cases (n = 8,16,32,64) in integer arithmetic; n>=91 clamps; float path
// has >=0.015 margin in value space vs ~1e-6 fp32 error.
__device__ __forceinline__ int t5_bucket(int delta) {
  int n = -delta;  // n = q - k
  int ret = 0;
  if (n < 0) { ret = 16; n = -n; }
  if (n < 8) return n + ret;
  if (n >= 91) return 15 + ret;
  if ((n & (n - 1)) == 0) {
    int l = 31 - __clz(n);
    int v = 2 + 2 * l;
    return (v > 15 ? 15 : v) + ret;
  }
  int v = 8 + (int)(logf((float)n * 0.125f) * (8.0f / logf(16.0f)));
  return (v > 15 ? 15 : v) + ret;
}

// ---------------- fp32 -> fp16 convert (hidden states) ----------------
__global__ void k_cvt(const float* __restrict__ src, _Float16* __restrict__ dst) {
  int t = blockIdx.x * 256 + threadIdx.x;
  float4 f = ((const float4*)src)[t];
  half4_t h = {(_Float16)f.x, (_Float16)f.y, (_Float16)f.z, (_Float16)f.w};
  ((half4_t*)dst)[t] = h;
}

// ---------------- fp32 1024x1024 transpose -> fp16 (all 4 weights, z = which) ----------
__global__ void k_wt_all(const float* __restrict__ Wq, const float* __restrict__ Wk,
                         const float* __restrict__ Wv, const float* __restrict__ Wo,
                         _Float16* __restrict__ wqkvT, _Float16* __restrict__ woT) {
  __shared__ float tile[32][33];
  const int z = blockIdx.z;
  const float* src = (z == 0) ? Wq : (z == 1) ? Wk : (z == 2) ? Wv : Wo;
  _Float16* dst = (z < 3) ? (wqkvT + ((size_t)z << 20)) : woT;
  int tx = threadIdx.x, ty = threadIdx.y;
  int bx = blockIdx.x * 32, by = blockIdx.y * 32;
#pragma unroll
  for (int i = 0; i < 32; i += 8)
    tile[ty + i][tx] = src[(size_t)(by + ty + i) * 1024 + bx + tx];
  __syncthreads();
#pragma unroll
  for (int i = 0; i < 32; i += 8)
    dst[(size_t)(bx + ty + i) * 1024 + by + tx] = (_Float16)tile[tx][ty + i];
}

// ---------------- QKV GEMM fused with position-bias writer ----------------
// 128x128 tile, BK=32, grid (24,32) = 768 blocks (~3/CU). Compute-bound GEMM with an
// idle HBM-write pipe: 512 of the blocks each stream a 512 KB bias slice
// (h = bid>>5, 64 q-rows x 2048 k) via 4 coalesced float4-stores per thread per K-iter.
// V-range blocks (n0 >= 2048) store the GEMM result transposed into vT.
__global__ __launch_bounds__(256, 2) void k_gemm_qkv_bias(
    const _Float16* __restrict__ A, const _Float16* __restrict__ BT,
    _Float16* __restrict__ qkv, _Float16* __restrict__ vT,
    const float* __restrict__ rel, float* __restrict__ outb) {
  __shared__ __align__(16) _Float16 As[128 * 32];
  __shared__ __align__(16) _Float16 Bs[128 * 32];
  __shared__ float btab[256];  // bias vs delta in [-128,127] (mixed band only)
  const int tid = threadIdx.x;
  const int wave = tid >> 6, lane = tid & 63;
  const int l15 = lane & 15, quad = lane >> 4;
  const int m0 = blockIdx.y * 128, n0 = blockIdx.x * 128;
  const int wm = (wave >> 1) * 64, wn = (wave & 1) * 64;
  const int r0 = tid >> 2, c0 = (tid & 3) * 8;
  constexpr int K = 1024;

  const int bid = blockIdx.y * 24 + blockIdx.x;  // 0..767
  const bool do_bias = bid < 512;
  const int hB = bid >> 5;              // head for this block's bias slice
  const int qoff = (bid & 31) * 64;     // 64-q strip within the head
  float c_past = 0.f, c_fut = 0.f;
  if (do_bias) {
    btab[tid & 255] = rel[t5_bucket((tid & 255) - 128) * 16 + hB];
    c_past = rel[15 * 16 + hB];
    c_fut = rel[31 * 16 + hB];
  }

  v4f acc[4][4] = {};
  for (int k0 = 0; k0 < K; k0 += 32) {
    __syncthreads();
    async_ld16(A + (size_t)(m0 + r0) * K + k0 + c0, (char*)As + (size_t)(wave * 64) * 16);
    async_ld16(A + (size_t)(m0 + 64 + r0) * K + k0 + c0,
               (char*)As + (size_t)(256 + wave * 64) * 16);
    async_ld16(BT + (size_t)(n0 + r0) * K + k0 + c0, (char*)Bs + (size_t)(wave * 64) * 16);
    async_ld16(BT + (size_t)(n0 + 64 + r0) * K + k0 + c0,
               (char*)Bs + (size_t)(256 + wave * 64) * 16);
    __syncthreads();

    // ---- bias strip: 1024 float4 (16 KB) per iter, fully coalesced ----
    if (do_bias) {
      const int iter = k0 >> 5;  // 0..31
#pragma unroll
      for (int j = 0; j < 4; ++j) {
        int fi = iter * 1024 + j * 256 + tid;  // 0..32767 within this block's slice
        int qr = qoff + (fi >> 9);
        int kb = (fi & 511) * 4;
        float4 v;
        if (kb - qr >= 91) {
          v = make_float4(c_fut, c_fut, c_fut, c_fut);
        } else if (qr - kb - 3 >= 91) {
          v = make_float4(c_past, c_past, c_past, c_past);
        } else {
          v.x = btab[kb + 0 - qr + 128];
          v.y = btab[kb + 1 - qr + 128];
          v.z = btab[kb + 2 - qr + 128];
          v.w = btab[kb + 3 - qr + 128];
        }
        ((float4*)outb)[(size_t)bid * 32768 + fi] = v;
      }
    }

    half8 af[4], bf[4];
#pragma unroll
    for (int mt = 0; mt < 4; ++mt)
      af[mt] = *(const half8*)(As + (wm + mt * 16 + l15) * 32 + quad * 8);
#pragma unroll
    for (int nt = 0; nt < 4; ++nt)
      bf[nt] = *(const half8*)(Bs + (wn + nt * 16 + l15) * 32 + quad * 8);
#pragma unroll
    for (int mt = 0; mt < 4; ++mt)
#pragma unroll
      for (int nt = 0; nt < 4; ++nt)
        acc[mt][nt] = __builtin_amdgcn_mfma_f32_16x16x32_f16(af[mt], bf[nt], acc[mt][nt], 0, 0, 0);
  }
  if (n0 >= 2048) {
    // V block: write vT[((b*16+h)*64+d)][s], 4 consecutive s per lane -> b64 stores
#pragma unroll
    for (int mt = 0; mt < 4; ++mt)
#pragma unroll
      for (int nt = 0; nt < 4; ++nt) {
        int col = n0 + wn + nt * 16 + l15 - 2048;  // h*64 + d
        int row0 = m0 + wm + mt * 16 + quad * 4;   // token
        int bb = row0 >> 11, s0 = row0 & 2047;
        half4_t hv = {(_Float16)acc[mt][nt][0], (_Float16)acc[mt][nt][1],
                      (_Float16)acc[mt][nt][2], (_Float16)acc[mt][nt][3]};
        *(half4_t*)(vT + ((size_t)bb * 1024 + col) * 2048 + s0) = hv;
      }
    return;
  }
#pragma unroll
  for (int mt = 0; mt < 4; ++mt)
#pragma unroll
    for (int nt = 0; nt < 4; ++nt)
#pragma unroll
      for (int r = 0; r < 4; ++r)
        qkv[(size_t)(m0 + wm + mt * 16 + quad * 4 + r) * 3072 + n0 + wn + nt * 16 + l15] =
            (_Float16)acc[mt][nt][r];
}

// ---------------- output projection GEMM: 128x64 tile ----------------
__global__ __launch_bounds__(256, 2) void k_gemm_n64(const _Float16* __restrict__ A,
                                                     const _Float16* __restrict__ BT,
                                                     float* __restrict__ C, int K, int ldc) {
  __shared__ __align__(16) _Float16 As[128 * 32];
  __shared__ __align__(16) _Float16 Bs[64 * 32];
  const int tid = threadIdx.x;
  const int wave = tid >> 6, lane = tid & 63;
  const int l15 = lane & 15, quad = lane >> 4;
  const int m0 = blockIdx.y * 128, n0 = blockIdx.x * 64;
  const int wm = (wave >> 1) * 64, wn = (wave & 1) * 32;
  const int r0 = tid >> 2, c0 = (tid & 3) * 8;
  v4f acc[4][2] = {};
  for (int k0 = 0; k0 < K; k0 += 32) {
    __syncthreads();
    async_ld16(A + (size_t)(m0 + r0) * K + k0 + c0, (char*)As + (size_t)(wave * 64) * 16);
    async_ld16(A + (size_t)(m0 + 64 + r0) * K + k0 + c0,
               (char*)As + (size_t)(256 + wave * 64) * 16);
    async_ld16(BT + (size_t)(n0 + r0) * K + k0 + c0, (char*)Bs + (size_t)(wave * 64) * 16);
    __syncthreads();
    half8 af[4], bf[2];
#pragma unroll
    for (int mt = 0; mt < 4; ++mt)
      af[mt] = *(const half8*)(As + (wm + mt * 16 + l15) * 32 + quad * 8);
#pragma unroll
    for (int nt = 0; nt < 2; ++nt)
      bf[nt] = *(const half8*)(Bs + (wn + nt * 16 + l15) * 32 + quad * 8);
#pragma unroll
    for (int mt = 0; mt < 4; ++mt)
#pragma unroll
      for (int nt = 0; nt < 2; ++nt)
        acc[mt][nt] = __builtin_amdgcn_mfma_f32_16x16x32_f16(af[mt], bf[nt], acc[mt][nt], 0, 0, 0);
  }
#pragma unroll
  for (int mt = 0; mt < 4; ++mt)
#pragma unroll
    for (int nt = 0; nt < 2; ++nt)
#pragma unroll
      for (int r = 0; r < 4; ++r)
        C[(size_t)(m0 + wm + mt * 16 + quad * 4 + r) * ldc + n0 + wn + nt * 16 + l15] =
            acc[mt][nt][r];
}

// ---------------- fused flash attention, operand-swapped (q = N dim) ----------------
// R2-proven config: grid (16,16,2) = 512 blocks (2/CU), 4 waves, wave owns 32 q (qt=2).
// Two barriers per kv tile (P round-trip needs none: each wave reads only its own rows).
__global__ __launch_bounds__(256, 3) void k_attn(const _Float16* __restrict__ qkv,
                                                 const _Float16* __restrict__ vT,
                                                 const float* __restrict__ mask,
                                                 const float* __restrict__ rel,
                                                 _Float16* __restrict__ ctx) {
  constexpr int S = 2048, LD = 3072;
  __shared__ __align__(16) _Float16 Ks[64 * 72];    // [kv][d] pad->LD 72
  __shared__ __align__(16) _Float16 VT[64 * 72];    // [d][kv]
  __shared__ __align__(16) _Float16 Psh[128 * 72];  // [q][kv] per-wave-owned rows
  __shared__ float btab[512];                       // bias vs delta in [-256,255]
  const int tid = threadIdx.x, wave = tid >> 6, lane = tid & 63;
  const int l15 = lane & 15, quad = lane >> 4;
  const int q0 = blockIdx.x * 128, h = blockIdx.y, b = blockIdx.z;

  for (int j = tid; j < 512; j += 256) btab[j] = rel[t5_bucket(j - 256) * 16 + h];
  const float c_past = rel[15 * 16 + h];  // q - k >= 91
  const float c_fut = rel[31 * 16 + h];   // k - q >= 91

  half8 bq[2][2];
#pragma unroll
  for (int qt = 0; qt < 2; ++qt) {
    const _Float16* qp = qkv + (size_t)(b * S + q0 + wave * 32 + qt * 16 + l15) * LD + h * 64;
    bq[qt][0] = *(const half8*)(qp + quad * 8);
    bq[qt][1] = *(const half8*)(qp + 32 + quad * 8);
  }
  v4f o[2][4] = {};
  float mrun[2] = {-INFINITY, -INFINITY};
  float lrun[2] = {0.f, 0.f};

  const int srow = tid >> 2, scol = (tid & 3) * 8;
  const _Float16* kg = qkv + (size_t)(b * S + srow) * LD + 1024 + h * 64 + scol;
  const _Float16* vg = vT + ((size_t)((b * 16 + h) * 64 + srow)) * S + scol;
  const float4* mkp = (const float4*)(mask + (size_t)b * S);

  for (int kv0 = 0; kv0 < S; kv0 += 64) {
    // global prefetch overlaps the barrier wait
    half8 kr0 = *(const half8*)(kg + (size_t)kv0 * LD);
    half8 kr1 = *(const half8*)(kg + (size_t)kv0 * LD + 32);
    half8 vr0 = *(const half8*)(vg + kv0);
    half8 vr1 = *(const half8*)(vg + kv0 + 32);
    float4 mk[4];
#pragma unroll
    for (int mt = 0; mt < 4; ++mt) mk[mt] = mkp[(kv0 >> 2) + mt * 4 + quad];
    __syncthreads();  // prev-iter Ks/VT reads done
    *(half8*)(Ks + srow * 72 + scol) = kr0;
    *(half8*)(Ks + srow * 72 + scol + 32) = kr1;
    *(half8*)(VT + srow * 72 + scol) = vr0;
    *(half8*)(VT + srow * 72 + scol + 32) = vr1;
    __syncthreads();  // staging visible

    // S^T: sc[qt][mt][r] = score(kv = kv0+mt*16+quad*4+r, q = q0+wave*32+qt*16+l15)
    v4f sc[2][4] = {};
#pragma unroll
    for (int kc = 0; kc < 2; ++kc)
#pragma unroll
      for (int mt = 0; mt < 4; ++mt) {
        half8 af = *(const half8*)(Ks + (mt * 16 + l15) * 72 + kc * 32 + quad * 8);
        sc[0][mt] = __builtin_amdgcn_mfma_f32_16x16x32_f16(af, bq[0][kc], sc[0][mt], 0, 0, 0);
        sc[1][mt] = __builtin_amdgcn_mfma_f32_16x16x32_f16(af, bq[1][kc], sc[1][mt], 0, 0, 0);
      }

    // bias + mask; block-uniform tile classification (diff is a multiple of 64, so
    // mixed tiles have delta in [-255,255] -> btab[512] exactly covers them)
    const int diff = kv0 - q0;
    const bool mixed = (diff >= -153) && (diff <= 217);
    const float cf = (diff >= 218) ? c_fut : c_past;
    v4f cm[4];
#pragma unroll
    for (int mt = 0; mt < 4; ++mt) {
      cm[mt][0] = mk[mt].x; cm[mt][1] = mk[mt].y; cm[mt][2] = mk[mt].z; cm[mt][3] = mk[mt].w;
      if (!mixed) {
        cm[mt][0] += cf; cm[mt][1] += cf; cm[mt][2] += cf; cm[mt][3] += cf;
      }
    }
    if (mixed) {
#pragma unroll
      for (int qt = 0; qt < 2; ++qt) {
        const int qq = q0 + wave * 32 + qt * 16 + l15;
#pragma unroll
        for (int mt = 0; mt < 4; ++mt) {
          int base = kv0 + mt * 16 + quad * 4 - qq + 256;
#pragma unroll
          for (int r = 0; r < 4; ++r) sc[qt][mt][r] += btab[base + r] + cm[mt][r];
        }
      }
    } else {
#pragma unroll
      for (int qt = 0; qt < 2; ++qt)
#pragma unroll
        for (int mt = 0; mt < 4; ++mt)
#pragma unroll
          for (int r = 0; r < 4; ++r) sc[qt][mt][r] += cm[mt][r];
    }

    // online softmax (one q per lane per qt; reduce across quads: xor 16, 32)
#pragma unroll
    for (int qt = 0; qt < 2; ++qt) {
      v4f m4 = sc[qt][0];
#pragma unroll
      for (int r = 0; r < 4; ++r) {
        m4[r] = fmaxf(m4[r], sc[qt][1][r]);
        m4[r] = fmaxf(m4[r], sc[qt][2][r]);
        m4[r] = fmaxf(m4[r], sc[qt][3][r]);
      }
      float mx = fmaxf(fmaxf(m4[0], m4[1]), fmaxf(m4[2], m4[3]));
      mx = fmaxf(mx, __shfl_xor(mx, 16, 64));
      mx = fmaxf(mx, __shfl_xor(mx, 32, 64));
      float mnew = fmaxf(mrun[qt], mx);
      float alpha = __expf(mrun[qt] - mnew);
      mrun[qt] = mnew;
      v4f s4 = {};
#pragma unroll
      for (int mt = 0; mt < 4; ++mt)
#pragma unroll
        for (int r = 0; r < 4; ++r) {
          float p = __expf(sc[qt][mt][r] - mnew);
          sc[qt][mt][r] = p;
          s4[r] += p;
        }
      float rs = (s4[0] + s4[1]) + (s4[2] + s4[3]);
      rs += __shfl_xor(rs, 16, 64);
      rs += __shfl_xor(rs, 32, 64);
      lrun[qt] = lrun[qt] * alpha + rs;
#pragma unroll
      for (int dt = 0; dt < 4; ++dt)
#pragma unroll
        for (int r = 0; r < 4; ++r) o[qt][dt][r] *= alpha;
      // P write: 4 consecutive kv per lane -> packed b64 (own-wave rows only)
      const int prow = wave * 32 + qt * 16 + l15;
#pragma unroll
      for (int mt = 0; mt < 4; ++mt) {
        half4_t ph = {(_Float16)sc[qt][mt][0], (_Float16)sc[qt][mt][1],
                      (_Float16)sc[qt][mt][2], (_Float16)sc[qt][mt][3]};
        *(half4_t*)(Psh + prow * 72 + mt * 16 + quad * 4) = ph;
      }
    }
    // NO barrier: PV reads only this wave's own P rows (same-wave LDS RAW -> lgkmcnt)

    // O^T += V^T * P^T
#pragma unroll
    for (int kc = 0; kc < 2; ++kc) {
      half8 bp0 = *(const half8*)(Psh + (wave * 32 + l15) * 72 + kc * 32 + quad * 8);
      half8 bp1 = *(const half8*)(Psh + (wave * 32 + 16 + l15) * 72 + kc * 32 + quad * 8);
#pragma unroll
      for (int dt = 0; dt < 4; ++dt) {
        half8 av = *(const half8*)(VT + (dt * 16 + l15) * 72 + kc * 32 + quad * 8);
        o[0][dt] = __builtin_amdgcn_mfma_f32_16x16x32_f16(av, bp0, o[0][dt], 0, 0, 0);
        o[1][dt] = __builtin_amdgcn_mfma_f32_16x16x32_f16(av, bp1, o[1][dt], 0, 0, 0);
      }
    }
  }
  // epilogue: ctx[token][h*64+d], d = dt*16 + quad*4 + r
#pragma unroll
  for (int qt = 0; qt < 2; ++qt) {
    float inv = 1.0f / lrun[qt];
    const size_t token = (size_t)(b * S + q0 + wave * 32 + qt * 16 + l15);
#pragma unroll
    for (int dt = 0; dt < 4; ++dt) {
      half4_t hv = {(_Float16)(o[qt][dt][0] * inv), (_Float16)(o[qt][dt][1] * inv),
                    (_Float16)(o[qt][dt][2] * inv), (_Float16)(o[qt][dt][3] * inv)};
      *(half4_t*)(ctx + token * 1024 + h * 64 + dt * 16 + quad * 4) = hv;
    }
  }
}

extern "C" void kernel_launch(void* const* d_in, const int* in_sizes, int n_in,
                              void* d_out, int out_size, void* d_ws, size_t ws_size,
                              hipStream_t stream) {
  const float* hs = (const float*)d_in[0];
  const float* mask = (const float*)d_in[1];
  const float* Wq = (const float*)d_in[2];
  const float* Wk = (const float*)d_in[3];
  const float* Wv = (const float*)d_in[4];
  const float* Wo = (const float*)d_in[5];
  const float* rel = (const float*)d_in[6];
  float* out = (float*)d_out;

  // workspace layout (56 MB)
  char* ws = (char*)d_ws;
  _Float16* hsF = (_Float16*)(ws);                 // [4096,1024]   8 MB
  _Float16* wqkvT = (_Float16*)(ws + (8u << 20));  // [3072,1024]   6 MB
  _Float16* woT = (_Float16*)(ws + (14u << 20));   // [1024,1024]   2 MB
  _Float16* qkv = (_Float16*)(ws + (16u << 20));   // [4096,3072]  24 MB (V-part unused)
  _Float16* ctx = (_Float16*)(ws + (40u << 20));   // [4096,1024]   8 MB
  _Float16* vT = (_Float16*)(ws + (48u << 20));    // [2,16,64,2048] 8 MB

  k_cvt<<<4096, 256, 0, stream>>>(hs, hsF);
  k_wt_all<<<dim3(32, 32, 4), dim3(32, 8), 0, stream>>>(Wq, Wk, Wv, Wo, wqkvT, woT);

  // QKV projection fused with the 268 MB bias-output stream (idle write pipe there);
  // V-range blocks write vT directly (transposed epilogue)
  k_gemm_qkv_bias<<<dim3(24, 32), 256, 0, stream>>>(hsF, wqkvT, qkv, vT, rel,
                                                    out + 4194304);
  // fused flash attention (R2-proven config, one barrier removed)
  k_attn<<<dim3(16, 16, 2), 256, 0, stream>>>(qkv, vT, mask, rel, ctx);
  // output projection
  k_gemm_n64<<<dim3(16, 32), 256, 0, stream>>>(ctx, woT, out, 1024, 1024);
}

// Round 7
// 425.010 us; speedup vs baseline: 1.1365x; 1.0241x over previous
//
#include <hip/hip_runtime.h>
#include <cstdint>

#define AS1 __attribute__((address_space(1)))
#define AS3 __attribute__((address_space(3)))

typedef _Float16 half8 __attribute__((ext_vector_type(8)));
typedef _Float16 half4_t __attribute__((ext_vector_type(4)));
typedef float v4f __attribute__((ext_vector_type(4)));

__device__ __forceinline__ void async_ld16(const void* g, void* l) {
  __builtin_amdgcn_global_load_lds((const AS1 uint32_t*)g, (AS3 uint32_t*)l, 16, 0, 0);
}

// T5 relative-position bucket for delta = k - q (bidirectional, 32 buckets, max_dist 128).
// Exact-boundary cases (n = 8,16,32,64) in integer arithmetic; n>=91 clamps; float path
// has >=0.015 margin in value space vs ~1e-6 fp32 error.
__device__ __forceinline__ int t5_bucket(int delta) {
  int n = -delta;  // n = q - k
  int ret = 0;
  if (n < 0) { ret = 16; n = -n; }
  if (n < 8) return n + ret;
  if (n >= 91) return 15 + ret;
  if ((n & (n - 1)) == 0) {
    int l = 31 - __clz(n);
    int v = 2 + 2 * l;
    return (v > 15 ? 15 : v) + ret;
  }
  int v = 8 + (int)(logf((float)n * 0.125f) * (8.0f / logf(16.0f)));
  return (v > 15 ? 15 : v) + ret;
}

// ---------------- prep: hs fp32->fp16 (x<4096) + 4 weight transposes (x>=4096) --------
__global__ void k_prep(const float* __restrict__ hs, const float* __restrict__ Wq,
                       const float* __restrict__ Wk, const float* __restrict__ Wv,
                       const float* __restrict__ Wo, _Float16* __restrict__ hsF,
                       _Float16* __restrict__ wqkvT, _Float16* __restrict__ woT) {
  const int tid = threadIdx.x;
  if (blockIdx.x < 4096) {
    int t = blockIdx.x * 256 + tid;
    float4 f = ((const float4*)hs)[t];
    half4_t h = {(_Float16)f.x, (_Float16)f.y, (_Float16)f.z, (_Float16)f.w};
    ((half4_t*)hsF)[t] = h;
    return;
  }
  __shared__ float tile[32][33];
  const int idx = blockIdx.x - 4096;
  const int z = idx >> 10, rem = idx & 1023;
  const float* src = (z == 0) ? Wq : (z == 1) ? Wk : (z == 2) ? Wv : Wo;
  _Float16* dst = (z < 3) ? (wqkvT + ((size_t)z << 20)) : woT;
  const int tx = tid & 31, ty = tid >> 5;
  const int bx = (rem & 31) * 32, by = (rem >> 5) * 32;
#pragma unroll
  for (int i = 0; i < 32; i += 8)
    tile[ty + i][tx] = src[(size_t)(by + ty + i) * 1024 + bx + tx];
  __syncthreads();
#pragma unroll
  for (int i = 0; i < 32; i += 8)
    dst[(size_t)(bx + ty + i) * 1024 + by + tx] = (_Float16)tile[tx][ty + i];
}

// ---------------- QKV GEMM fused with position-bias writer ----------------
// 128x128 tile, BK=32, grid (24,32) = 768 blocks (~3/CU). Compute-bound GEMM with an
// idle HBM-write pipe: 512 of the blocks each stream a 512 KB bias slice
// (h = bid>>5, 64 q-rows x 2048 k) via 4 coalesced float4-stores per thread per K-iter.
// V-range blocks (n0 >= 2048) store the GEMM result transposed into vT.
__global__ __launch_bounds__(256, 2) void k_gemm_qkv_bias(
    const _Float16* __restrict__ A, const _Float16* __restrict__ BT,
    _Float16* __restrict__ qkv, _Float16* __restrict__ vT,
    const float* __restrict__ rel, float* __restrict__ outb) {
  __shared__ __align__(16) _Float16 As[128 * 32];
  __shared__ __align__(16) _Float16 Bs[128 * 32];
  __shared__ float btab[256];  // bias vs delta in [-128,127] (mixed band only)
  const int tid = threadIdx.x;
  const int wave = tid >> 6, lane = tid & 63;
  const int l15 = lane & 15, quad = lane >> 4;
  const int m0 = blockIdx.y * 128, n0 = blockIdx.x * 128;
  const int wm = (wave >> 1) * 64, wn = (wave & 1) * 64;
  const int r0 = tid >> 2, c0 = (tid & 3) * 8;
  constexpr int K = 1024;

  const int bid = blockIdx.y * 24 + blockIdx.x;  // 0..767
  const bool do_bias = bid < 512;
  const int hB = bid >> 5;           // head for this block's bias slice
  const int qoff = (bid & 31) * 64;  // 64-q strip within the head
  float c_past = 0.f, c_fut = 0.f;
  if (do_bias) {
    btab[tid & 255] = rel[t5_bucket((tid & 255) - 128) * 16 + hB];
    c_past = rel[15 * 16 + hB];
    c_fut = rel[31 * 16 + hB];
  }

  v4f acc[4][4] = {};
  for (int k0 = 0; k0 < K; k0 += 32) {
    __syncthreads();
    async_ld16(A + (size_t)(m0 + r0) * K + k0 + c0, (char*)As + (size_t)(wave * 64) * 16);
    async_ld16(A + (size_t)(m0 + 64 + r0) * K + k0 + c0,
               (char*)As + (size_t)(256 + wave * 64) * 16);
    async_ld16(BT + (size_t)(n0 + r0) * K + k0 + c0, (char*)Bs + (size_t)(wave * 64) * 16);
    async_ld16(BT + (size_t)(n0 + 64 + r0) * K + k0 + c0,
               (char*)Bs + (size_t)(256 + wave * 64) * 16);
    __syncthreads();

    // ---- bias strip: 1024 float4 (16 KB) per iter, fully coalesced ----
    if (do_bias) {
      const int iter = k0 >> 5;  // 0..31
#pragma unroll
      for (int j = 0; j < 4; ++j) {
        int fi = iter * 1024 + j * 256 + tid;  // 0..32767 within this block's slice
        int qr = qoff + (fi >> 9);
        int kb = (fi & 511) * 4;
        float4 v;
        if (kb - qr >= 91) {
          v = make_float4(c_fut, c_fut, c_fut, c_fut);
        } else if (qr - kb - 3 >= 91) {
          v = make_float4(c_past, c_past, c_past, c_past);
        } else {
          v.x = btab[kb + 0 - qr + 128];
          v.y = btab[kb + 1 - qr + 128];
          v.z = btab[kb + 2 - qr + 128];
          v.w = btab[kb + 3 - qr + 128];
        }
        ((float4*)outb)[(size_t)bid * 32768 + fi] = v;
      }
    }

    half8 af[4], bf[4];
#pragma unroll
    for (int mt = 0; mt < 4; ++mt)
      af[mt] = *(const half8*)(As + (wm + mt * 16 + l15) * 32 + quad * 8);
#pragma unroll
    for (int nt = 0; nt < 4; ++nt)
      bf[nt] = *(const half8*)(Bs + (wn + nt * 16 + l15) * 32 + quad * 8);
#pragma unroll
    for (int mt = 0; mt < 4; ++mt)
#pragma unroll
      for (int nt = 0; nt < 4; ++nt)
        acc[mt][nt] = __builtin_amdgcn_mfma_f32_16x16x32_f16(af[mt], bf[nt], acc[mt][nt], 0, 0, 0);
  }
  if (n0 >= 2048) {
    // V block: write vT[((b*16+h)*64+d)][s], 4 consecutive s per lane -> b64 stores
#pragma unroll
    for (int mt = 0; mt < 4; ++mt)
#pragma unroll
      for (int nt = 0; nt < 4; ++nt) {
        int col = n0 + wn + nt * 16 + l15 - 2048;  // h*64 + d
        int row0 = m0 + wm + mt * 16 + quad * 4;   // token
        int bb = row0 >> 11, s0 = row0 & 2047;
        half4_t hv = {(_Float16)acc[mt][nt][0], (_Float16)acc[mt][nt][1],
                      (_Float16)acc[mt][nt][2], (_Float16)acc[mt][nt][3]};
        *(half4_t*)(vT + ((size_t)bb * 1024 + col) * 2048 + s0) = hv;
      }
    return;
  }
#pragma unroll
  for (int mt = 0; mt < 4; ++mt)
#pragma unroll
    for (int nt = 0; nt < 4; ++nt)
#pragma unroll
      for (int r = 0; r < 4; ++r)
        qkv[(size_t)(m0 + wm + mt * 16 + quad * 4 + r) * 3072 + n0 + wn + nt * 16 + l15] =
            (_Float16)acc[mt][nt][r];
}

// ---------------- output projection GEMM: 128x64 tile ----------------
__global__ __launch_bounds__(256, 2) void k_gemm_n64(const _Float16* __restrict__ A,
                                                     const _Float16* __restrict__ BT,
                                                     float* __restrict__ C, int K, int ldc) {
  __shared__ __align__(16) _Float16 As[128 * 32];
  __shared__ __align__(16) _Float16 Bs[64 * 32];
  const int tid = threadIdx.x;
  const int wave = tid >> 6, lane = tid & 63;
  const int l15 = lane & 15, quad = lane >> 4;
  const int m0 = blockIdx.y * 128, n0 = blockIdx.x * 64;
  const int wm = (wave >> 1) * 64, wn = (wave & 1) * 32;
  const int r0 = tid >> 2, c0 = (tid & 3) * 8;
  v4f acc[4][2] = {};
  for (int k0 = 0; k0 < K; k0 += 32) {
    __syncthreads();
    async_ld16(A + (size_t)(m0 + r0) * K + k0 + c0, (char*)As + (size_t)(wave * 64) * 16);
    async_ld16(A + (size_t)(m0 + 64 + r0) * K + k0 + c0,
               (char*)As + (size_t)(256 + wave * 64) * 16);
    async_ld16(BT + (size_t)(n0 + r0) * K + k0 + c0, (char*)Bs + (size_t)(wave * 64) * 16);
    __syncthreads();
    half8 af[4], bf[2];
#pragma unroll
    for (int mt = 0; mt < 4; ++mt)
      af[mt] = *(const half8*)(As + (wm + mt * 16 + l15) * 32 + quad * 8);
#pragma unroll
    for (int nt = 0; nt < 2; ++nt)
      bf[nt] = *(const half8*)(Bs + (wn + nt * 16 + l15) * 32 + quad * 8);
#pragma unroll
    for (int mt = 0; mt < 4; ++mt)
#pragma unroll
      for (int nt = 0; nt < 2; ++nt)
        acc[mt][nt] = __builtin_amdgcn_mfma_f32_16x16x32_f16(af[mt], bf[nt], acc[mt][nt], 0, 0, 0);
  }
#pragma unroll
  for (int mt = 0; mt < 4; ++mt)
#pragma unroll
    for (int nt = 0; nt < 2; ++nt)
#pragma unroll
      for (int r = 0; r < 4; ++r)
        C[(size_t)(m0 + wm + mt * 16 + quad * 4 + r) * ldc + n0 + wn + nt * 16 + l15] =
            acc[mt][nt][r];
}

// ---------------- fused flash attention, double-buffered K/V, 1 barrier/iter ----------
// grid (16,16,2) = 512 blocks (2/CU), 4 waves, wave owns 32 q (qt=2).
// Pipeline: prefetch tile i+1 globals during compute of tile i; stage into buf^1 after
// compute (no reader conflict); single end-of-iter barrier. P round-trip stays
// barrier-free (each wave reads only its own P rows).
__global__ __launch_bounds__(256, 2) void k_attn(const _Float16* __restrict__ qkv,
                                                 const _Float16* __restrict__ vT,
                                                 const float* __restrict__ mask,
                                                 const float* __restrict__ rel,
                                                 _Float16* __restrict__ ctx) {
  constexpr int S = 2048, LD = 3072;
  __shared__ __align__(16) _Float16 Ks[2][64 * 72];  // [buf][kv][d] pad->LD 72
  __shared__ __align__(16) _Float16 VT[2][64 * 72];  // [buf][d][kv]
  __shared__ __align__(16) _Float16 Psh[128 * 72];   // [q][kv] per-wave-owned rows
  __shared__ float btab[512];                        // bias vs delta in [-256,255]
  const int tid = threadIdx.x, wave = tid >> 6, lane = tid & 63;
  const int l15 = lane & 15, quad = lane >> 4;
  const int q0 = blockIdx.x * 128, h = blockIdx.y, b = blockIdx.z;

  for (int j = tid; j < 512; j += 256) btab[j] = rel[t5_bucket(j - 256) * 16 + h];
  const float c_past = rel[15 * 16 + h];  // q - k >= 91
  const float c_fut = rel[31 * 16 + h];   // k - q >= 91

  half8 bq[2][2];
#pragma unroll
  for (int qt = 0; qt < 2; ++qt) {
    const _Float16* qp = qkv + (size_t)(b * S + q0 + wave * 32 + qt * 16 + l15) * LD + h * 64;
    bq[qt][0] = *(const half8*)(qp + quad * 8);
    bq[qt][1] = *(const half8*)(qp + 32 + quad * 8);
  }
  v4f o[2][4] = {};
  float mrun[2] = {-INFINITY, -INFINITY};
  float lrun[2] = {0.f, 0.f};

  const int srow = tid >> 2, scol = (tid & 3) * 8;
  const _Float16* kg = qkv + (size_t)(b * S + srow) * LD + 1024 + h * 64 + scol;
  const _Float16* vg = vT + ((size_t)((b * 16 + h) * 64 + srow)) * S + scol;
  const float4* mkp = (const float4*)(mask + (size_t)b * S);

  // stage tile 0 into buf 0
  {
    half8 kr0 = *(const half8*)(kg);
    half8 kr1 = *(const half8*)(kg + 32);
    half8 vr0 = *(const half8*)(vg);
    half8 vr1 = *(const half8*)(vg + 32);
    *(half8*)(&Ks[0][srow * 72 + scol]) = kr0;
    *(half8*)(&Ks[0][srow * 72 + scol + 32]) = kr1;
    *(half8*)(&VT[0][srow * 72 + scol]) = vr0;
    *(half8*)(&VT[0][srow * 72 + scol + 32]) = vr1;
  }
  float4 mk[4];
#pragma unroll
  for (int mt = 0; mt < 4; ++mt) mk[mt] = mkp[mt * 4 + quad];
  __syncthreads();  // tile0 + btab visible

  for (int kv0 = 0; kv0 < S; kv0 += 64) {
    const int buf = (kv0 >> 6) & 1;
    const bool more = (kv0 + 64) < S;
    // prefetch tile i+1 globals (consumed after compute)
    half8 kr0n, kr1n, vr0n, vr1n;
    float4 mkn[4];
    if (more) {
      kr0n = *(const half8*)(kg + (size_t)(kv0 + 64) * LD);
      kr1n = *(const half8*)(kg + (size_t)(kv0 + 64) * LD + 32);
      vr0n = *(const half8*)(vg + kv0 + 64);
      vr1n = *(const half8*)(vg + kv0 + 64 + 32);
#pragma unroll
      for (int mt = 0; mt < 4; ++mt) mkn[mt] = mkp[((kv0 + 64) >> 2) + mt * 4 + quad];
    }

    // S^T: sc[qt][mt][r] = score(kv = kv0+mt*16+quad*4+r, q = q0+wave*32+qt*16+l15)
    const _Float16* KsB = &Ks[buf][0];
    const _Float16* VTB = &VT[buf][0];
    v4f sc[2][4] = {};
#pragma unroll
    for (int kc = 0; kc < 2; ++kc)
#pragma unroll
      for (int mt = 0; mt < 4; ++mt) {
        half8 af = *(const half8*)(KsB + (mt * 16 + l15) * 72 + kc * 32 + quad * 8);
        sc[0][mt] = __builtin_amdgcn_mfma_f32_16x16x32_f16(af, bq[0][kc], sc[0][mt], 0, 0, 0);
        sc[1][mt] = __builtin_amdgcn_mfma_f32_16x16x32_f16(af, bq[1][kc], sc[1][mt], 0, 0, 0);
      }

    // bias + mask; block-uniform tile classification (mixed deltas fit btab[512])
    const int diff = kv0 - q0;
    const bool mixed = (diff >= -153) && (diff <= 217);
    const float cf = (diff >= 218) ? c_fut : c_past;
    v4f cm[4];
#pragma unroll
    for (int mt = 0; mt < 4; ++mt) {
      cm[mt][0] = mk[mt].x; cm[mt][1] = mk[mt].y; cm[mt][2] = mk[mt].z; cm[mt][3] = mk[mt].w;
      if (!mixed) {
        cm[mt][0] += cf; cm[mt][1] += cf; cm[mt][2] += cf; cm[mt][3] += cf;
      }
    }
    if (mixed) {
#pragma unroll
      for (int qt = 0; qt < 2; ++qt) {
        const int qq = q0 + wave * 32 + qt * 16 + l15;
#pragma unroll
        for (int mt = 0; mt < 4; ++mt) {
          int base = kv0 + mt * 16 + quad * 4 - qq + 256;
#pragma unroll
          for (int r = 0; r < 4; ++r) sc[qt][mt][r] += btab[base + r] + cm[mt][r];
        }
      }
    } else {
#pragma unroll
      for (int qt = 0; qt < 2; ++qt)
#pragma unroll
        for (int mt = 0; mt < 4; ++mt)
#pragma unroll
          for (int r = 0; r < 4; ++r) sc[qt][mt][r] += cm[mt][r];
    }

    // online softmax (one q per lane per qt; reduce across quads: xor 16, 32)
#pragma unroll
    for (int qt = 0; qt < 2; ++qt) {
      v4f m4 = sc[qt][0];
#pragma unroll
      for (int r = 0; r < 4; ++r) {
        m4[r] = fmaxf(m4[r], sc[qt][1][r]);
        m4[r] = fmaxf(m4[r], sc[qt][2][r]);
        m4[r] = fmaxf(m4[r], sc[qt][3][r]);
      }
      float mx = fmaxf(fmaxf(m4[0], m4[1]), fmaxf(m4[2], m4[3]));
      mx = fmaxf(mx, __shfl_xor(mx, 16, 64));
      mx = fmaxf(mx, __shfl_xor(mx, 32, 64));
      float mnew = fmaxf(mrun[qt], mx);
      float alpha = __expf(mrun[qt] - mnew);
      mrun[qt] = mnew;
      v4f s4 = {};
#pragma unroll
      for (int mt = 0; mt < 4; ++mt)
#pragma unroll
        for (int r = 0; r < 4; ++r) {
          float p = __expf(sc[qt][mt][r] - mnew);
          sc[qt][mt][r] = p;
          s4[r] += p;
        }
      float rs = (s4[0] + s4[1]) + (s4[2] + s4[3]);
      rs += __shfl_xor(rs, 16, 64);
      rs += __shfl_xor(rs, 32, 64);
      lrun[qt] = lrun[qt] * alpha + rs;
#pragma unroll
      for (int dt = 0; dt < 4; ++dt)
#pragma unroll
        for (int r = 0; r < 4; ++r) o[qt][dt][r] *= alpha;
      // P write: 4 consecutive kv per lane -> packed b64 (own-wave rows only)
      const int prow = wave * 32 + qt * 16 + l15;
#pragma unroll
      for (int mt = 0; mt < 4; ++mt) {
        half4_t ph = {(_Float16)sc[qt][mt][0], (_Float16)sc[qt][mt][1],
                      (_Float16)sc[qt][mt][2], (_Float16)sc[qt][mt][3]};
        *(half4_t*)(Psh + prow * 72 + mt * 16 + quad * 4) = ph;
      }
    }
    // NO barrier: PV reads only this wave's own P rows (same-wave LDS RAW -> lgkmcnt)

    // O^T += V^T * P^T
#pragma unroll
    for (int kc = 0; kc < 2; ++kc) {
      half8 bp0 = *(const half8*)(Psh + (wave * 32 + l15) * 72 + kc * 32 + quad * 8);
      half8 bp1 = *(const half8*)(Psh + (wave * 32 + 16 + l15) * 72 + kc * 32 + quad * 8);
#pragma unroll
      for (int dt = 0; dt < 4; ++dt) {
        half8 av = *(const half8*)(VTB + (dt * 16 + l15) * 72 + kc * 32 + quad * 8);
        o[0][dt] = __builtin_amdgcn_mfma_f32_16x16x32_f16(av, bp0, o[0][dt], 0, 0, 0);
        o[1][dt] = __builtin_amdgcn_mfma_f32_16x16x32_f16(av, bp1, o[1][dt], 0, 0, 0);
      }
    }

    // stage tile i+1 into the other buffer; single barrier closes the iteration
    if (more) {
      _Float16* Kn = &Ks[buf ^ 1][0];
      _Float16* Vn = &VT[buf ^ 1][0];
      *(half8*)(Kn + srow * 72 + scol) = kr0n;
      *(half8*)(Kn + srow * 72 + scol + 32) = kr1n;
      *(half8*)(Vn + srow * 72 + scol) = vr0n;
      *(half8*)(Vn + srow * 72 + scol + 32) = vr1n;
      __syncthreads();
#pragma unroll
      for (int mt = 0; mt < 4; ++mt) mk[mt] = mkn[mt];
    }
  }
  // epilogue: ctx[token][h*64+d], d = dt*16 + quad*4 + r
#pragma unroll
  for (int qt = 0; qt < 2; ++qt) {
    float inv = 1.0f / lrun[qt];
    const size_t token = (size_t)(b * S + q0 + wave * 32 + qt * 16 + l15);
#pragma unroll
    for (int dt = 0; dt < 4; ++dt) {
      half4_t hv = {(_Float16)(o[qt][dt][0] * inv), (_Float16)(o[qt][dt][1] * inv),
                    (_Float16)(o[qt][dt][2] * inv), (_Float16)(o[qt][dt][3] * inv)};
      *(half4_t*)(ctx + token * 1024 + h * 64 + dt * 16 + quad * 4) = hv;
    }
  }
}

extern "C" void kernel_launch(void* const* d_in, const int* in_sizes, int n_in,
                              void* d_out, int out_size, void* d_ws, size_t ws_size,
                              hipStream_t stream) {
  const float* hs = (const float*)d_in[0];
  const float* mask = (const float*)d_in[1];
  const float* Wq = (const float*)d_in[2];
  const float* Wk = (const float*)d_in[3];
  const float* Wv = (const float*)d_in[4];
  const float* Wo = (const float*)d_in[5];
  const float* rel = (const float*)d_in[6];
  float* out = (float*)d_out;

  // workspace layout (56 MB)
  char* ws = (char*)d_ws;
  _Float16* hsF = (_Float16*)(ws);                 // [4096,1024]   8 MB
  _Float16* wqkvT = (_Float16*)(ws + (8u << 20));  // [3072,1024]   6 MB
  _Float16* woT = (_Float16*)(ws + (14u << 20));   // [1024,1024]   2 MB
  _Float16* qkv = (_Float16*)(ws + (16u << 20));   // [4096,3072]  24 MB (V-part unused)
  _Float16* ctx = (_Float16*)(ws + (40u << 20));   // [4096,1024]   8 MB
  _Float16* vT = (_Float16*)(ws + (48u << 20));    // [2,16,64,2048] 8 MB

  // prep: hs convert + all 4 weight transposes in one dispatch
  k_prep<<<8192, 256, 0, stream>>>(hs, Wq, Wk, Wv, Wo, hsF, wqkvT, woT);

  // QKV projection fused with the 268 MB bias-output stream (idle write pipe there);
  // V-range blocks write vT directly (transposed epilogue)
  k_gemm_qkv_bias<<<dim3(24, 32), 256, 0, stream>>>(hsF, wqkvT, qkv, vT, rel,
                                                    out + 4194304);
  // fused flash attention (double-buffered K/V, 1 barrier per kv tile)
  k_attn<<<dim3(16, 16, 2), 256, 0, stream>>>(qkv, vT, mask, rel, ctx);
  // output projection
  k_gemm_n64<<<dim3(16, 32), 256, 0, stream>>>(ctx, woT, out, 1024, 1024);
}